// Round 2
// baseline (637.119 us; speedup 1.0000x reference)
//
#include <hip/hip_runtime.h>
#include <hip/hip_bf16.h>

#define NN 50000
#define NE 800000
#define FIN 128
#define HD 64
#define NC 40

// uniform-lane broadcast via v_readlane (SGPR result, no LDS pipe)
__device__ __forceinline__ float bcastf(float v, int l){
  return __uint_as_float((unsigned)__builtin_amdgcn_readlane((int)__float_as_uint(v), l));
}

__global__ void k_zero(int* __restrict__ cnt){
  int i = blockIdx.x*256 + threadIdx.x;
  if (i < NN) cnt[i] = 0;
}

__global__ void k_count(const int* __restrict__ ei, int* __restrict__ cnt){
  int e = blockIdx.x*256 + threadIdx.x;
  if (e < NE) atomicAdd(&cnt[ei[NE + e]], 1);
}

// single-block exclusive scan over NN counts -> rowptr[NN+1], cursor copy
__global__ void k_scan(const int* __restrict__ cnt, int* __restrict__ rowptr,
                       int* __restrict__ cursor){
  __shared__ int sh[1024];
  const int t = threadIdx.x;
  const int per = (NN + 1023) / 1024;   // 49
  const int beg = t * per;
  const int end = (beg + per < NN) ? (beg + per) : NN;
  int s = 0;
  for (int i = beg; i < end; ++i) s += cnt[i];
  sh[t] = s;
  __syncthreads();
  for (int off = 1; off < 1024; off <<= 1){
    int v = sh[t];
    int a = (t >= off) ? sh[t - off] : 0;
    __syncthreads();
    sh[t] = v + a;
    __syncthreads();
  }
  int excl = (t == 0) ? 0 : sh[t - 1];
  for (int i = beg; i < end; ++i){
    rowptr[i] = excl;
    cursor[i] = excl;
    excl += cnt[i];
  }
  if (t == 1023) rowptr[NN] = sh[1023];
}

__global__ void k_fill(const int* __restrict__ ei, int* __restrict__ cursor,
                       int* __restrict__ esrc){
  int e = blockIdx.x*256 + threadIdx.x;
  if (e < NE){
    int d = ei[NE + e];
    int p = atomicAdd(&cursor[d], 1);
    esrc[p] = ei[e];
  }
}

// h0 = x_h @ W_init + b_init ; hyp = tanh(pos @ W_pos + b_pos)
// wave per node, lane = output column; weight columns live in VGPRs.
__global__ __launch_bounds__(256, 2) void k_init(
    const float* __restrict__ x, const float* __restrict__ pos,
    const float* __restrict__ Wi, const float* __restrict__ bi,
    const float* __restrict__ Wp, const float* __restrict__ bp,
    float* __restrict__ h0, float* __restrict__ hyp){
  const int lane = threadIdx.x & 63;
  const int wid  = blockIdx.x * 4 + (threadIdx.x >> 6);
  const int nw   = gridDim.x * 4;
  float wi[FIN];
  #pragma unroll
  for (int k = 0; k < FIN; ++k) wi[k] = Wi[k*HD + lane];
  float wp[16];
  #pragma unroll
  for (int k = 0; k < 16; ++k) wp[k] = Wp[k*HD + lane];
  const float bib = bi[lane];
  const float bpb = bp[lane];
  for (int n = wid; n < NN; n += nw){
    const float* xr = x + (size_t)n * FIN;
    float x0 = xr[lane];
    float x1 = xr[64 + lane];
    float pv = (lane < 16) ? pos[n*16 + lane] : 0.f;
    float acc = bib;
    #pragma unroll
    for (int k = 0; k < 64; ++k){
      acc += bcastf(x0, k) * wi[k];
      acc += bcastf(x1, k) * wi[64 + k];
    }
    float ap = bpb;
    #pragma unroll
    for (int k = 0; k < 16; ++k) ap += bcastf(pv, k) * wp[k];
    h0[n*HD + lane]  = acc;
    hyp[n*HD + lane] = tanhf(ap);
  }
}

// one SAGE layer: out = mean_nbr(hin) @ Wl + hin @ Wr + b  (+hyp, relu)
__global__ __launch_bounds__(256, 2) void k_layer(
    const float* __restrict__ hin, float* __restrict__ hout,
    const float* __restrict__ hyp,
    const int* __restrict__ rowptr, const int* __restrict__ esrc,
    const float* __restrict__ Wl, const float* __restrict__ Wr,
    const float* __restrict__ bc, const int do_relu){
  const int lane = threadIdx.x & 63;
  const int wid  = blockIdx.x * 4 + (threadIdx.x >> 6);
  const int nw   = gridDim.x * 4;
  float wl[HD], wr[HD];
  #pragma unroll
  for (int k = 0; k < HD; ++k){
    wl[k] = Wl[k*HD + lane];
    wr[k] = Wr[k*HD + lane];
  }
  const float bb = bc[lane];
  for (int n = wid; n < NN; n += nw){
    const int r0 = rowptr[n], r1 = rowptr[n + 1];
    float s0 = 0.f, s1 = 0.f, s2 = 0.f, s3 = 0.f;
    for (int base = r0; base < r1; base += 64){
      const int rem = r1 - base;
      const int m   = rem < 64 ? rem : 64;
      int sidx = (lane < rem) ? esrc[base + lane] : 0;
      int t = 0;
      for (; t + 3 < m; t += 4){
        int a = __builtin_amdgcn_readlane(sidx, t);
        int b = __builtin_amdgcn_readlane(sidx, t + 1);
        int c = __builtin_amdgcn_readlane(sidx, t + 2);
        int d = __builtin_amdgcn_readlane(sidx, t + 3);
        s0 += hin[(size_t)a*HD + lane];
        s1 += hin[(size_t)b*HD + lane];
        s2 += hin[(size_t)c*HD + lane];
        s3 += hin[(size_t)d*HD + lane];
      }
      for (; t < m; ++t){
        int a = __builtin_amdgcn_readlane(sidx, t);
        s0 += hin[(size_t)a*HD + lane];
      }
    }
    const int deg = r1 - r0;
    const float mean = deg > 0 ? (s0 + s1 + s2 + s3) / (float)deg : 0.f;
    const float hv = hin[(size_t)n*HD + lane];
    float acc = bb;
    #pragma unroll
    for (int k = 0; k < HD; ++k){
      acc += bcastf(mean, k) * wl[k];
      acc += bcastf(hv,   k) * wr[k];
    }
    if (do_relu){
      acc += hyp[n*HD + lane];
      acc = fmaxf(acc, 0.f);
    }
    hout[n*HD + lane] = acc;
  }
}

// emb = h @ W_last + b_last ; out = [emb ; log_softmax(emb)]
__global__ __launch_bounds__(256, 2) void k_final(
    const float* __restrict__ hin, const float* __restrict__ Wl,
    const float* __restrict__ bl, float* __restrict__ out){
  const int lane = threadIdx.x & 63;
  const int wid  = blockIdx.x * 4 + (threadIdx.x >> 6);
  const int nw   = gridDim.x * 4;
  const int c = lane < NC ? lane : 0;
  float w[HD];
  #pragma unroll
  for (int k = 0; k < HD; ++k) w[k] = Wl[k*NC + c];
  const float bb = bl[c];
  for (int n = wid; n < NN; n += nw){
    const float hv = hin[(size_t)n*HD + lane];
    float acc = bb;
    #pragma unroll
    for (int k = 0; k < HD; ++k) acc += bcastf(hv, k) * w[k];
    float vmax = (lane < NC) ? acc : -3.4e38f;
    #pragma unroll
    for (int off = 32; off; off >>= 1)
      vmax = fmaxf(vmax, __shfl_xor(vmax, off, 64));
    float ex = (lane < NC) ? __expf(acc - vmax) : 0.f;
    float s = ex;
    #pragma unroll
    for (int off = 32; off; off >>= 1)
      s += __shfl_xor(s, off, 64);
    const float lsm = acc - vmax - __logf(s);
    if (lane < NC){
      out[(size_t)n*NC + lane]                 = acc;
      out[(size_t)NN*NC + (size_t)n*NC + lane] = lsm;
    }
  }
}

extern "C" void kernel_launch(void* const* d_in, const int* in_sizes, int n_in,
                              void* d_out, int out_size, void* d_ws, size_t ws_size,
                              hipStream_t stream){
  (void)in_sizes; (void)n_in; (void)out_size; (void)ws_size;
  const float* x_h    = (const float*)d_in[0];
  const float* pos    = (const float*)d_in[1];
  const int*   ei     = (const int*)  d_in[2];
  const float* W_pos  = (const float*)d_in[3];
  const float* b_pos  = (const float*)d_in[4];
  const float* W_init = (const float*)d_in[5];
  const float* b_init = (const float*)d_in[6];
  const float* W_l    = (const float*)d_in[7];
  const float* W_r    = (const float*)d_in[8];
  const float* b_conv = (const float*)d_in[9];
  const float* W_last = (const float*)d_in[10];
  const float* b_last = (const float*)d_in[11];
  float* out = (float*)d_out;

  char* p = (char*)d_ws;
  auto alloc = [&](size_t bytes)->char*{
    char* r = p; p += (bytes + 255) & ~(size_t)255; return r;
  };
  float* hyp   = (float*)alloc((size_t)NN*HD*4);
  float* hA    = (float*)alloc((size_t)NN*HD*4);
  float* hB    = (float*)alloc((size_t)NN*HD*4);
  int* cnt     = (int*)alloc((size_t)NN*4);
  int* rowptr  = (int*)alloc((size_t)(NN+1)*4);
  int* cursor  = (int*)alloc((size_t)NN*4);
  int* esrc    = (int*)alloc((size_t)NE*4);

  k_zero <<<(NN + 255)/256, 256, 0, stream>>>(cnt);
  k_count<<<(NE + 255)/256, 256, 0, stream>>>(ei, cnt);
  k_scan <<<1, 1024, 0, stream>>>(cnt, rowptr, cursor);
  k_fill <<<(NE + 255)/256, 256, 0, stream>>>(ei, cursor, esrc);
  k_init <<<512, 256, 0, stream>>>(x_h, pos, W_init, b_init, W_pos, b_pos, hA, hyp);
  k_layer<<<1024, 256, 0, stream>>>(hA, hB, hyp, rowptr, esrc,
                                    W_l,           W_r,           b_conv,        1);
  k_layer<<<1024, 256, 0, stream>>>(hB, hA, hyp, rowptr, esrc,
                                    W_l + HD*HD,   W_r + HD*HD,   b_conv + HD,   1);
  k_layer<<<1024, 256, 0, stream>>>(hA, hB, hyp, rowptr, esrc,
                                    W_l + 2*HD*HD, W_r + 2*HD*HD, b_conv + 2*HD, 0);
  k_final<<<512, 256, 0, stream>>>(hB, W_last, b_last, out);
}

// Round 3
// 530.239 us; speedup vs baseline: 1.2016x; 1.2016x over previous
//
#include <hip/hip_runtime.h>
#include <hip/hip_bf16.h>

#define NN 50000
#define NE 800000
#define FIN 128
#define HD 64
#define NC 40
#define NB 196   // ceil(NN/256)

// uniform-lane broadcast via v_readlane (SGPR result, no LDS pipe)
__device__ __forceinline__ float bcastf(float v, int l){
  return __uint_as_float((unsigned)__builtin_amdgcn_readlane((int)__float_as_uint(v), l));
}

__global__ void k_count(const int* __restrict__ ei, int* __restrict__ cnt){
  int e = blockIdx.x*256 + threadIdx.x;
  if (e < NE) atomicAdd(&cnt[ei[NE + e]], 1);
}

// per-block sum of 256 counts -> bsum[block]
__global__ void k_bsum(const int* __restrict__ cnt, int* __restrict__ bsum){
  const int t = threadIdx.x;
  const int i = blockIdx.x*256 + t;
  int v = (i < NN) ? cnt[i] : 0;
  #pragma unroll
  for (int off = 32; off; off >>= 1) v += __shfl_xor(v, off, 64);
  __shared__ int sw[4];
  if ((t & 63) == 0) sw[t >> 6] = v;
  __syncthreads();
  if (t == 0) bsum[blockIdx.x] = sw[0] + sw[1] + sw[2] + sw[3];
}

// single small block: exclusive scan of NB block sums
__global__ void k_bscan(const int* __restrict__ bsum, int* __restrict__ boff){
  __shared__ int sh[256];
  const int t = threadIdx.x;
  int v = (t < NB) ? bsum[t] : 0;
  sh[t] = v;
  __syncthreads();
  #pragma unroll
  for (int off = 1; off < 256; off <<= 1){
    int a = (t >= off) ? sh[t - off] : 0;
    __syncthreads();
    sh[t] += a;
    __syncthreads();
  }
  if (t < NB) boff[t] = sh[t] - v;   // exclusive
}

// per-block local scan + block offset -> rowptr, cursor
__global__ void k_rowptr(const int* __restrict__ cnt, const int* __restrict__ boff,
                         int* __restrict__ rowptr, int* __restrict__ cursor){
  __shared__ int sh[256];
  const int t = threadIdx.x;
  const int i = blockIdx.x*256 + t;
  int v = (i < NN) ? cnt[i] : 0;
  sh[t] = v;
  __syncthreads();
  #pragma unroll
  for (int off = 1; off < 256; off <<= 1){
    int a = (t >= off) ? sh[t - off] : 0;
    __syncthreads();
    sh[t] += a;
    __syncthreads();
  }
  if (i < NN){
    int excl = sh[t] - v + boff[blockIdx.x];
    rowptr[i] = excl;
    cursor[i] = excl;
  }
  if (i == 0) rowptr[NN] = NE;  // every edge has a destination
}

__global__ void k_fill(const int* __restrict__ ei, int* __restrict__ cursor,
                       int* __restrict__ esrc){
  int e = blockIdx.x*256 + threadIdx.x;
  if (e < NE){
    int d = ei[NE + e];
    int p = atomicAdd(&cursor[d], 1);
    esrc[p] = ei[e];
  }
}

// h0 = x_h @ W_init + b_init ; hyp = tanh(pos @ W_pos + b_pos)
// wave per node, lane = output column; weight columns live in VGPRs.
__global__ __launch_bounds__(256, 2) void k_init(
    const float* __restrict__ x, const float* __restrict__ pos,
    const float* __restrict__ Wi, const float* __restrict__ bi,
    const float* __restrict__ Wp, const float* __restrict__ bp,
    float* __restrict__ h0, float* __restrict__ hyp){
  const int lane = threadIdx.x & 63;
  const int wid  = blockIdx.x * 4 + (threadIdx.x >> 6);
  const int nw   = gridDim.x * 4;
  float wi[FIN];
  #pragma unroll
  for (int k = 0; k < FIN; ++k) wi[k] = Wi[k*HD + lane];
  float wp[16];
  #pragma unroll
  for (int k = 0; k < 16; ++k) wp[k] = Wp[k*HD + lane];
  const float bib = bi[lane];
  const float bpb = bp[lane];
  for (int n = wid; n < NN; n += nw){
    const float* xr = x + (size_t)n * FIN;
    float x0 = xr[lane];
    float x1 = xr[64 + lane];
    float pv = (lane < 16) ? pos[n*16 + lane] : 0.f;
    float acc = bib;
    #pragma unroll
    for (int k = 0; k < 64; ++k){
      acc += bcastf(x0, k) * wi[k];
      acc += bcastf(x1, k) * wi[64 + k];
    }
    float ap = bpb;
    #pragma unroll
    for (int k = 0; k < 16; ++k) ap += bcastf(pv, k) * wp[k];
    h0[n*HD + lane]  = acc;
    hyp[n*HD + lane] = tanhf(ap);
  }
}

// one SAGE layer: out = mean_nbr(hin) @ Wl + hin @ Wr + b  (+hyp, relu)
__global__ __launch_bounds__(256, 2) void k_layer(
    const float* __restrict__ hin, float* __restrict__ hout,
    const float* __restrict__ hyp,
    const int* __restrict__ rowptr, const int* __restrict__ esrc,
    const float* __restrict__ Wl, const float* __restrict__ Wr,
    const float* __restrict__ bc, const int do_relu){
  const int lane = threadIdx.x & 63;
  const int wid  = blockIdx.x * 4 + (threadIdx.x >> 6);
  const int nw   = gridDim.x * 4;
  float wl[HD], wr[HD];
  #pragma unroll
  for (int k = 0; k < HD; ++k){
    wl[k] = Wl[k*HD + lane];
    wr[k] = Wr[k*HD + lane];
  }
  const float bb = bc[lane];
  for (int n = wid; n < NN; n += nw){
    const int r0 = rowptr[n], r1 = rowptr[n + 1];
    float s0=0.f,s1=0.f,s2=0.f,s3=0.f,s4=0.f,s5=0.f,s6=0.f,s7=0.f;
    for (int base = r0; base < r1; base += 64){
      const int rem = r1 - base;
      const int m   = rem < 64 ? rem : 64;
      int sidx = (lane < rem) ? esrc[base + lane] : 0;
      int t = 0;
      for (; t + 7 < m; t += 8){
        int a0 = __builtin_amdgcn_readlane(sidx, t);
        int a1 = __builtin_amdgcn_readlane(sidx, t + 1);
        int a2 = __builtin_amdgcn_readlane(sidx, t + 2);
        int a3 = __builtin_amdgcn_readlane(sidx, t + 3);
        int a4 = __builtin_amdgcn_readlane(sidx, t + 4);
        int a5 = __builtin_amdgcn_readlane(sidx, t + 5);
        int a6 = __builtin_amdgcn_readlane(sidx, t + 6);
        int a7 = __builtin_amdgcn_readlane(sidx, t + 7);
        s0 += hin[(size_t)a0*HD + lane];
        s1 += hin[(size_t)a1*HD + lane];
        s2 += hin[(size_t)a2*HD + lane];
        s3 += hin[(size_t)a3*HD + lane];
        s4 += hin[(size_t)a4*HD + lane];
        s5 += hin[(size_t)a5*HD + lane];
        s6 += hin[(size_t)a6*HD + lane];
        s7 += hin[(size_t)a7*HD + lane];
      }
      for (; t < m; ++t){
        int a = __builtin_amdgcn_readlane(sidx, t);
        s0 += hin[(size_t)a*HD + lane];
      }
    }
    const int deg = r1 - r0;
    const float sum = ((s0+s1)+(s2+s3)) + ((s4+s5)+(s6+s7));
    const float mean = deg > 0 ? sum / (float)deg : 0.f;
    const float hv = hin[(size_t)n*HD + lane];
    float acc = bb;
    #pragma unroll
    for (int k = 0; k < HD; ++k){
      acc += bcastf(mean, k) * wl[k];
      acc += bcastf(hv,   k) * wr[k];
    }
    if (do_relu){
      acc += hyp[n*HD + lane];
      acc = fmaxf(acc, 0.f);
    }
    hout[n*HD + lane] = acc;
  }
}

// emb = h @ W_last + b_last ; out = [emb ; log_softmax(emb)]
__global__ __launch_bounds__(256, 2) void k_final(
    const float* __restrict__ hin, const float* __restrict__ Wl,
    const float* __restrict__ bl, float* __restrict__ out){
  const int lane = threadIdx.x & 63;
  const int wid  = blockIdx.x * 4 + (threadIdx.x >> 6);
  const int nw   = gridDim.x * 4;
  const int c = lane < NC ? lane : 0;
  float w[HD];
  #pragma unroll
  for (int k = 0; k < HD; ++k) w[k] = Wl[k*NC + c];
  const float bb = bl[c];
  for (int n = wid; n < NN; n += nw){
    const float hv = hin[(size_t)n*HD + lane];
    float acc = bb;
    #pragma unroll
    for (int k = 0; k < HD; ++k) acc += bcastf(hv, k) * w[k];
    float vmax = (lane < NC) ? acc : -3.4e38f;
    #pragma unroll
    for (int off = 32; off; off >>= 1)
      vmax = fmaxf(vmax, __shfl_xor(vmax, off, 64));
    float ex = (lane < NC) ? __expf(acc - vmax) : 0.f;
    float s = ex;
    #pragma unroll
    for (int off = 32; off; off >>= 1)
      s += __shfl_xor(s, off, 64);
    const float lsm = acc - vmax - __logf(s);
    if (lane < NC){
      out[(size_t)n*NC + lane]                 = acc;
      out[(size_t)NN*NC + (size_t)n*NC + lane] = lsm;
    }
  }
}

extern "C" void kernel_launch(void* const* d_in, const int* in_sizes, int n_in,
                              void* d_out, int out_size, void* d_ws, size_t ws_size,
                              hipStream_t stream){
  (void)in_sizes; (void)n_in; (void)out_size; (void)ws_size;
  const float* x_h    = (const float*)d_in[0];
  const float* pos    = (const float*)d_in[1];
  const int*   ei     = (const int*)  d_in[2];
  const float* W_pos  = (const float*)d_in[3];
  const float* b_pos  = (const float*)d_in[4];
  const float* W_init = (const float*)d_in[5];
  const float* b_init = (const float*)d_in[6];
  const float* W_l    = (const float*)d_in[7];
  const float* W_r    = (const float*)d_in[8];
  const float* b_conv = (const float*)d_in[9];
  const float* W_last = (const float*)d_in[10];
  const float* b_last = (const float*)d_in[11];
  float* out = (float*)d_out;

  char* p = (char*)d_ws;
  auto alloc = [&](size_t bytes)->char*{
    char* r = p; p += (bytes + 255) & ~(size_t)255; return r;
  };
  float* hyp   = (float*)alloc((size_t)NN*HD*4);
  float* hA    = (float*)alloc((size_t)NN*HD*4);
  float* hB    = (float*)alloc((size_t)NN*HD*4);
  int* cnt     = (int*)alloc((size_t)NN*4);
  int* rowptr  = (int*)alloc((size_t)(NN+1)*4);
  int* cursor  = (int*)alloc((size_t)NN*4);
  int* esrc    = (int*)alloc((size_t)NE*4);
  int* bsum    = (int*)alloc((size_t)NB*4);
  int* boff    = (int*)alloc((size_t)NB*4);

  hipMemsetAsync(cnt, 0, (size_t)NN*4, stream);
  k_count <<<(NE + 255)/256, 256, 0, stream>>>(ei, cnt);
  k_bsum  <<<NB, 256, 0, stream>>>(cnt, bsum);
  k_bscan <<<1, 256, 0, stream>>>(bsum, boff);
  k_rowptr<<<NB, 256, 0, stream>>>(cnt, boff, rowptr, cursor);
  k_fill  <<<(NE + 255)/256, 256, 0, stream>>>(ei, cursor, esrc);
  k_init  <<<512, 256, 0, stream>>>(x_h, pos, W_init, b_init, W_pos, b_pos, hA, hyp);
  k_layer <<<1024, 256, 0, stream>>>(hA, hB, hyp, rowptr, esrc,
                                     W_l,           W_r,           b_conv,        1);
  k_layer <<<1024, 256, 0, stream>>>(hB, hA, hyp, rowptr, esrc,
                                     W_l + HD*HD,   W_r + HD*HD,   b_conv + HD,   1);
  k_layer <<<1024, 256, 0, stream>>>(hA, hB, hyp, rowptr, esrc,
                                     W_l + 2*HD*HD, W_r + 2*HD*HD, b_conv + 2*HD, 0);
  k_final <<<512, 256, 0, stream>>>(hB, W_last, b_last, out);
}

// Round 4
// 441.332 us; speedup vs baseline: 1.4436x; 1.2015x over previous
//
#include <hip/hip_runtime.h>
#include <hip/hip_bf16.h>

#define NN 50000
#define NE 800000
#define FIN 128
#define HD 64
#define NC 40
#define NB 196   // ceil(NN/256)

// uniform-lane broadcast via v_readlane (SGPR result, no LDS pipe)
__device__ __forceinline__ float bcastf(float v, int l){
  return __uint_as_float((unsigned)__builtin_amdgcn_readlane((int)__float_as_uint(v), l));
}

__global__ void k_count(const int* __restrict__ ei, int* __restrict__ cnt){
  int e = blockIdx.x*256 + threadIdx.x;
  if (e < NE) atomicAdd(&cnt[ei[NE + e]], 1);
}

__global__ void k_bsum(const int* __restrict__ cnt, int* __restrict__ bsum){
  const int t = threadIdx.x;
  const int i = blockIdx.x*256 + t;
  int v = (i < NN) ? cnt[i] : 0;
  #pragma unroll
  for (int off = 32; off; off >>= 1) v += __shfl_xor(v, off, 64);
  __shared__ int sw[4];
  if ((t & 63) == 0) sw[t >> 6] = v;
  __syncthreads();
  if (t == 0) bsum[blockIdx.x] = sw[0] + sw[1] + sw[2] + sw[3];
}

__global__ void k_bscan(const int* __restrict__ bsum, int* __restrict__ boff){
  __shared__ int sh[256];
  const int t = threadIdx.x;
  int v = (t < NB) ? bsum[t] : 0;
  sh[t] = v;
  __syncthreads();
  #pragma unroll
  for (int off = 1; off < 256; off <<= 1){
    int a = (t >= off) ? sh[t - off] : 0;
    __syncthreads();
    sh[t] += a;
    __syncthreads();
  }
  if (t < NB) boff[t] = sh[t] - v;   // exclusive
}

__global__ void k_rowptr(const int* __restrict__ cnt, const int* __restrict__ boff,
                         int* __restrict__ rowptr, int* __restrict__ cursor){
  __shared__ int sh[256];
  const int t = threadIdx.x;
  const int i = blockIdx.x*256 + t;
  int v = (i < NN) ? cnt[i] : 0;
  sh[t] = v;
  __syncthreads();
  #pragma unroll
  for (int off = 1; off < 256; off <<= 1){
    int a = (t >= off) ? sh[t - off] : 0;
    __syncthreads();
    sh[t] += a;
    __syncthreads();
  }
  if (i < NN){
    int excl = sh[t] - v + boff[blockIdx.x];
    rowptr[i] = excl;
    cursor[i] = excl;
  }
  if (i == 0) rowptr[NN] = NE;
}

__global__ void k_fill(const int* __restrict__ ei, int* __restrict__ cursor,
                       int* __restrict__ esrc){
  int e = blockIdx.x*256 + threadIdx.x;
  if (e < NE){
    int d = ei[NE + e];
    int p = atomicAdd(&cursor[d], 1);
    esrc[p] = ei[e];
  }
}

// h0 = x_h @ W_init + b_init ; hyp = tanh(pos @ W_pos + b_pos)
__global__ __launch_bounds__(256, 2) void k_init(
    const float* __restrict__ x, const float* __restrict__ pos,
    const float* __restrict__ Wi, const float* __restrict__ bi,
    const float* __restrict__ Wp, const float* __restrict__ bp,
    float* __restrict__ h0, float* __restrict__ hyp){
  const int lane = threadIdx.x & 63;
  const int wid  = blockIdx.x * 4 + (threadIdx.x >> 6);
  const int nw   = gridDim.x * 4;
  float wi[FIN];
  #pragma unroll
  for (int k = 0; k < FIN; ++k) wi[k] = Wi[k*HD + lane];
  float wp[16];
  #pragma unroll
  for (int k = 0; k < 16; ++k) wp[k] = Wp[k*HD + lane];
  const float bib = bi[lane];
  const float bpb = bp[lane];
  for (int n = wid; n < NN; n += nw){
    const float* xr = x + (size_t)n * FIN;
    float x0 = xr[lane];
    float x1 = xr[64 + lane];
    float pv = (lane < 16) ? pos[n*16 + lane] : 0.f;
    float acc = bib;
    #pragma unroll
    for (int k = 0; k < 64; ++k){
      acc += bcastf(x0, k) * wi[k];
      acc += bcastf(x1, k) * wi[64 + k];
    }
    float ap = bpb;
    #pragma unroll
    for (int k = 0; k < 16; ++k) ap += bcastf(pv, k) * wp[k];
    h0[n*HD + lane]  = acc;
    hyp[n*HD + lane] = tanhf(ap);
  }
}

// y = h @ Wl (in-place over h) ; z = h @ Wr + b (+ hyp)
// NOTE: h/y may alias (each wave reads row n fully into a register before
// writing it) -- no __restrict__ on those params.
__global__ __launch_bounds__(256) void k_xform(
    const float* h, const float* __restrict__ Wl,
    const float* __restrict__ Wr, const float* __restrict__ bc,
    const float* __restrict__ hyp, const int use_hyp,
    float* y, float* __restrict__ z){
  const int lane = threadIdx.x & 63;
  const int wid  = blockIdx.x * 4 + (threadIdx.x >> 6);
  const int nw   = gridDim.x * 4;
  float wl[HD], wr[HD];
  #pragma unroll
  for (int k = 0; k < HD; ++k){
    wl[k] = Wl[k*HD + lane];
    wr[k] = Wr[k*HD + lane];
  }
  const float bb = bc[lane];
  for (int n = wid; n < NN; n += nw){
    const float hv = h[(size_t)n*HD + lane];
    float ay = 0.f, az = bb;
    #pragma unroll
    for (int k = 0; k < HD; ++k){
      const float s = bcastf(hv, k);
      ay += s * wl[k];
      az += s * wr[k];
    }
    if (use_hyp) az += hyp[(size_t)n*HD + lane];
    y[(size_t)n*HD + lane] = ay;
    z[(size_t)n*HD + lane] = az;
  }
}

// out = [relu]( sum_{j in N(n)} y_j / deg + z_n )
// wave per node; lane = (eslot 0..3) x (feature-quad 0..15); float4 gathers
// cover 4 neighbor rows per instruction. z/out alias in-place (row n only).
__global__ __launch_bounds__(256) void k_gather(
    const float* __restrict__ y, const float* z,
    const int* __restrict__ rowptr, const int* __restrict__ esrc,
    float* out, const int do_relu){
  const int lane  = threadIdx.x & 63;
  const int n     = blockIdx.x * 4 + (threadIdx.x >> 6);
  if (n >= NN) return;
  const int fq    = lane & 15;
  const int eslot = lane >> 4;
  const int r0 = rowptr[n], r1 = rowptr[n + 1];
  float4 acc = {0.f, 0.f, 0.f, 0.f};
  for (int base = r0; base < r1; base += 64){
    const int cdeg   = min(64, r1 - base);
    const int rounds = (cdeg + 3) >> 2;
    #pragma unroll 4
    for (int i = 0; i < rounds; ++i){
      const int e = (i << 2) + eslot;
      if (e < cdeg){
        const int s = esrc[base + e];
        const float4 v = *(const float4*)(y + (size_t)s*HD + fq*4);
        acc.x += v.x; acc.y += v.y; acc.z += v.z; acc.w += v.w;
      }
    }
  }
  #pragma unroll
  for (int m = 16; m <= 32; m <<= 1){
    acc.x += __shfl_xor(acc.x, m, 64);
    acc.y += __shfl_xor(acc.y, m, 64);
    acc.z += __shfl_xor(acc.z, m, 64);
    acc.w += __shfl_xor(acc.w, m, 64);
  }
  if (eslot == 0){
    const int deg = r1 - r0;
    const float inv = deg > 0 ? 1.f / (float)deg : 0.f;
    const float4 zv = *(const float4*)(z + (size_t)n*HD + fq*4);
    float4 o;
    o.x = acc.x*inv + zv.x;
    o.y = acc.y*inv + zv.y;
    o.z = acc.z*inv + zv.z;
    o.w = acc.w*inv + zv.w;
    if (do_relu){
      o.x = fmaxf(o.x, 0.f); o.y = fmaxf(o.y, 0.f);
      o.z = fmaxf(o.z, 0.f); o.w = fmaxf(o.w, 0.f);
    }
    *(float4*)(out + (size_t)n*HD + fq*4) = o;
  }
}

// emb = h @ W_last + b_last ; out = [emb ; log_softmax(emb)]
__global__ __launch_bounds__(256, 2) void k_final(
    const float* __restrict__ hin, const float* __restrict__ Wl,
    const float* __restrict__ bl, float* __restrict__ out){
  const int lane = threadIdx.x & 63;
  const int wid  = blockIdx.x * 4 + (threadIdx.x >> 6);
  const int nw   = gridDim.x * 4;
  const int c = lane < NC ? lane : 0;
  float w[HD];
  #pragma unroll
  for (int k = 0; k < HD; ++k) w[k] = Wl[k*NC + c];
  const float bb = bl[c];
  for (int n = wid; n < NN; n += nw){
    const float hv = hin[(size_t)n*HD + lane];
    float acc = bb;
    #pragma unroll
    for (int k = 0; k < HD; ++k) acc += bcastf(hv, k) * w[k];
    float vmax = (lane < NC) ? acc : -3.4e38f;
    #pragma unroll
    for (int off = 32; off; off >>= 1)
      vmax = fmaxf(vmax, __shfl_xor(vmax, off, 64));
    float ex = (lane < NC) ? __expf(acc - vmax) : 0.f;
    float s = ex;
    #pragma unroll
    for (int off = 32; off; off >>= 1)
      s += __shfl_xor(s, off, 64);
    const float lsm = acc - vmax - __logf(s);
    if (lane < NC){
      out[(size_t)n*NC + lane]                 = acc;
      out[(size_t)NN*NC + (size_t)n*NC + lane] = lsm;
    }
  }
}

extern "C" void kernel_launch(void* const* d_in, const int* in_sizes, int n_in,
                              void* d_out, int out_size, void* d_ws, size_t ws_size,
                              hipStream_t stream){
  (void)in_sizes; (void)n_in; (void)out_size; (void)ws_size;
  const float* x_h    = (const float*)d_in[0];
  const float* pos    = (const float*)d_in[1];
  const int*   ei     = (const int*)  d_in[2];
  const float* W_pos  = (const float*)d_in[3];
  const float* b_pos  = (const float*)d_in[4];
  const float* W_init = (const float*)d_in[5];
  const float* b_init = (const float*)d_in[6];
  const float* W_l    = (const float*)d_in[7];
  const float* W_r    = (const float*)d_in[8];
  const float* b_conv = (const float*)d_in[9];
  const float* W_last = (const float*)d_in[10];
  const float* b_last = (const float*)d_in[11];
  float* out = (float*)d_out;

  char* p = (char*)d_ws;
  auto alloc = [&](size_t bytes)->char*{
    char* r = p; p += (bytes + 255) & ~(size_t)255; return r;
  };
  float* hyp   = (float*)alloc((size_t)NN*HD*4);
  float* hA    = (float*)alloc((size_t)NN*HD*4);
  float* hB    = (float*)alloc((size_t)NN*HD*4);
  int* cnt     = (int*)alloc((size_t)NN*4);
  int* rowptr  = (int*)alloc((size_t)(NN+1)*4);
  int* cursor  = (int*)alloc((size_t)NN*4);
  int* esrc    = (int*)alloc((size_t)NE*4);
  int* bsum    = (int*)alloc((size_t)NB*4);
  int* boff    = (int*)alloc((size_t)NB*4);

  hipMemsetAsync(cnt, 0, (size_t)NN*4, stream);
  k_count <<<(NE + 255)/256, 256, 0, stream>>>(ei, cnt);
  k_bsum  <<<NB, 256, 0, stream>>>(cnt, bsum);
  k_bscan <<<1, 256, 0, stream>>>(bsum, boff);
  k_rowptr<<<NB, 256, 0, stream>>>(cnt, boff, rowptr, cursor);
  k_fill  <<<(NE + 255)/256, 256, 0, stream>>>(ei, cursor, esrc);
  k_init  <<<512, 256, 0, stream>>>(x_h, pos, W_init, b_init, W_pos, b_pos, hA, hyp);

  float* cur = hA;
  float* nxt = hB;
  for (int l = 0; l < 3; ++l){
    const int last = (l == 2);
    // y -> in-place over cur ; z -> nxt
    k_xform <<<1024, 256, 0, stream>>>(cur, W_l + l*HD*HD, W_r + l*HD*HD,
                                       b_conv + l*HD, hyp, !last, cur, nxt);
    // out -> in-place over nxt (z)
    k_gather<<<(NN + 3)/4, 256, 0, stream>>>(cur, nxt, rowptr, esrc, nxt, !last);
    float* t = cur; cur = nxt; nxt = t;
  }
  k_final <<<512, 256, 0, stream>>>(cur, W_last, b_last, out);
}